// Round 3
// baseline (485.433 us; speedup 1.0000x reference)
//
#include <hip/hip_runtime.h>
#include <stdint.h>

#define BATCH 16
#define SEQ   1024
#define DIM   1024

static const size_t NE = (size_t)BATCH * SEQ * DIM;  // 16,777,216 elements per tensor

typedef short short8 __attribute__((ext_vector_type(8)));
typedef float f32x4  __attribute__((ext_vector_type(4)));

typedef __attribute__((address_space(1))) const unsigned int g_u32;
typedef __attribute__((address_space(3))) unsigned int l_u32;

__device__ __forceinline__ float bf2f(unsigned short u) {
  return __uint_as_float(((unsigned int)u) << 16);
}
__device__ __forceinline__ unsigned short f2bf(float f) {
  unsigned int u = __float_as_uint(f);
  u += 0x7FFFu + ((u >> 16) & 1u);   // RTN-even; inputs are finite normals
  return (unsigned short)(u >> 16);
}
__device__ __forceinline__ void gl_lds16(const unsigned short* g, unsigned short* l) {
  __builtin_amdgcn_global_load_lds((g_u32*)g, (l_u32*)l, 16, 0, 0);
}

// ---------------------------------------------------------------------------
// K0: fp32 -> bf16 copies + bf16 transposed copies + per-row inverse norms.
// One 64-row block per WG, loops 16 column tiles of 64; LDS 64x65 transpose.
// ---------------------------------------------------------------------------
__global__ __launch_bounds__(256) void k_cvt(
    const float* __restrict__ P, const float* __restrict__ Hp,
    unsigned short* __restrict__ P16, unsigned short* __restrict__ H16,
    unsigned short* __restrict__ P16T, unsigned short* __restrict__ H16T,
    float* __restrict__ invP, float* __restrict__ invH)
{
  const int b  = blockIdx.x;
  const int rb = blockIdx.y;     // 64-row block
  const float* src; unsigned short* dst; unsigned short* dstT; float* inv;
  if (blockIdx.z == 0) { src = P;  dst = P16; dstT = P16T; inv = invP; }
  else                 { src = Hp; dst = H16; dstT = H16T; inv = invH; }
  src  += (size_t)b*SEQ*DIM + (size_t)rb*64*DIM;
  dst  += (size_t)b*SEQ*DIM + (size_t)rb*64*DIM;
  dstT += (size_t)b*SEQ*DIM + (size_t)rb*64;   // [DIM][SEQ], col offset rb*64
  inv  += b*SEQ + rb*64;

  __shared__ unsigned short Ls[64*65];
  __shared__ float rowacc[64];
  const int t = threadIdx.x;
  if (t < 64) rowacc[t] = 0.f;
  __syncthreads();

  for (int ct = 0; ct < 16; ++ct) {
    #pragma unroll
    for (int round = 0; round < 4; ++round) {
      int idx = round*256 + t;          // float4 index within 64x64 tile
      int r = idx >> 4;                 // tile row
      int c = (idx & 15) * 4;           // float col within 64
      float4 x = *(const float4*)(src + (size_t)r*DIM + ct*64 + c);
      float ss = x.x*x.x + x.y*x.y + x.z*x.z + x.w*x.w;
      ss += __shfl_xor(ss, 1);
      ss += __shfl_xor(ss, 2);
      ss += __shfl_xor(ss, 4);
      ss += __shfl_xor(ss, 8);
      if ((t & 15) == 0) rowacc[r] += ss;   // unique leader thread per row
      unsigned short h0=f2bf(x.x), h1=f2bf(x.y), h2=f2bf(x.z), h3=f2bf(x.w);
      union { unsigned short us[4]; uint2 u; } pk;
      pk.us[0]=h0; pk.us[1]=h1; pk.us[2]=h2; pk.us[3]=h3;
      *(uint2*)(dst + (size_t)r*DIM + ct*64 + c) = pk.u;
      Ls[r*65 + c + 0] = h0;
      Ls[r*65 + c + 1] = h1;
      Ls[r*65 + c + 2] = h2;
      Ls[r*65 + c + 3] = h3;
    }
    __syncthreads();
    {
      int dloc = t >> 2;          // local d (0..63)
      int a0   = (t & 3) * 16;    // local a segment
      union { unsigned short us[16]; uint4 u[2]; } pk;
      #pragma unroll
      for (int jj = 0; jj < 16; ++jj) pk.us[jj] = Ls[(a0+jj)*65 + dloc];
      unsigned short* o = dstT + (size_t)(ct*64 + dloc)*SEQ + a0;
      *(uint4*)(o)     = pk.u[0];
      *(uint4*)(o + 8) = pk.u[1];
    }
    __syncthreads();
  }
  if (t < 64) inv[t] = rsqrtf(rowacc[t]);
}

// ---------------------------------------------------------------------------
// m97-style B^T GEMM, 128x128 tile, BK=32, 4 waves (2x2), 16x16x32 bf16 MFMA.
// MODE 0: C = bf16(exp(acc * sRow[r] * sCol[c]))   (score -> E)
// MODE 1: C = f32(acc * sRow[r])                   (PV -> output, softmax scale)
// A: [M][K] row-major, Bm: [N][K] row-major (B^T), all dims 1024, batched 16.
// ---------------------------------------------------------------------------
template<int MODE>
__global__ __launch_bounds__(256) void k_gemm(
    const unsigned short* __restrict__ A,
    const unsigned short* __restrict__ Bm,
    void* __restrict__ Cout,
    const float* __restrict__ sRow,
    const float* __restrict__ sCol)
{
  __shared__ unsigned short As[128*32];
  __shared__ unsigned short Bs[128*32];
  const int b    = blockIdx.x;
  const int brow = blockIdx.y * 128;
  const int bcol = blockIdx.z * 128;
  const int t = threadIdx.x;
  const int w = t >> 6, l = t & 63;
  const int wr = w >> 1, wc = w & 1;

  const size_t boff = (size_t)b << 20;
  const unsigned short* gA0 = A  + boff + (size_t)(brow + w*32 + (l>>2))*DIM + (l&3)*8;
  const unsigned short* gB0 = Bm + boff + (size_t)(bcol + w*32 + (l>>2))*DIM + (l&3)*8;
  unsigned short* lA0 = &As[(w*2+0)*512];
  unsigned short* lA1 = &As[(w*2+1)*512];
  unsigned short* lB0 = &Bs[(w*2+0)*512];
  unsigned short* lB1 = &Bs[(w*2+1)*512];

  f32x4 acc[4][4];
  #pragma unroll
  for (int m = 0; m < 4; ++m)
    #pragma unroll
    for (int n = 0; n < 4; ++n)
      acc[m][n] = (f32x4){0.f,0.f,0.f,0.f};

  const int fr = l & 15;
  const int kg = (l >> 4) * 8;

  for (int kt = 0; kt < 32; ++kt) {
    const int k0 = kt * 32;
    gl_lds16(gA0 + k0,          lA0);
    gl_lds16(gA0 + 16*DIM + k0, lA1);
    gl_lds16(gB0 + k0,          lB0);
    gl_lds16(gB0 + 16*DIM + k0, lB1);
    __syncthreads();
    short8 af[4], bf[4];
    #pragma unroll
    for (int m = 0; m < 4; ++m)
      af[m] = *(const short8*)&As[(wr*64 + m*16 + fr)*32 + kg];
    #pragma unroll
    for (int n = 0; n < 4; ++n)
      bf[n] = *(const short8*)&Bs[(wc*64 + n*16 + fr)*32 + kg];
    #pragma unroll
    for (int m = 0; m < 4; ++m)
      #pragma unroll
      for (int n = 0; n < 4; ++n)
        acc[m][n] = __builtin_amdgcn_mfma_f32_16x16x32_bf16(af[m], bf[n], acc[m][n], 0, 0, 0);
    __syncthreads();
  }

  const int rb0 = brow + wr*64 + ((l>>4)<<2);  // C/D: row=(lane>>4)*4+j
  const int cb0 = bcol + wc*64 + fr;           //       col=lane&15
  if (MODE == 0) {
    unsigned short* E = (unsigned short*)Cout + boff;
    #pragma unroll
    for (int n = 0; n < 4; ++n) {
      const int c = cb0 + n*16;
      const float ic = sCol[b*SEQ + c];
      #pragma unroll
      for (int m = 0; m < 4; ++m) {
        const int r0 = rb0 + m*16;
        #pragma unroll
        for (int j = 0; j < 4; ++j) {
          float s = acc[m][n][j] * sRow[b*SEQ + r0 + j] * ic;  // cosine in [-1,1]
          E[(size_t)(r0 + j)*SEQ + c] = f2bf(__expf(s));       // no max-sub needed
        }
      }
    }
  } else {
    float* C = (float*)Cout + boff;
    #pragma unroll
    for (int n = 0; n < 4; ++n) {
      const int c = cb0 + n*16;
      #pragma unroll
      for (int m = 0; m < 4; ++m) {
        const int r0 = rb0 + m*16;
        #pragma unroll
        for (int j = 0; j < 4; ++j)
          C[(size_t)(r0 + j)*SEQ + c] = acc[m][n][j] * sRow[b*SEQ + r0 + j];
      }
    }
  }
}

// ---------------------------------------------------------------------------
// Reciprocal row sums of a bf16 [rows][1024] matrix. One wave per row.
// ---------------------------------------------------------------------------
__global__ __launch_bounds__(256) void k_rowinv(
    const unsigned short* __restrict__ E, float* __restrict__ out)
{
  const int row = blockIdx.x*4 + (threadIdx.x >> 6);
  const int l = threadIdx.x & 63;
  const unsigned short* p = E + (size_t)row*SEQ + l*8;
  float s = 0.f;
  #pragma unroll
  for (int h = 0; h < 2; ++h) {
    union { uint4 u; unsigned short us[8]; } d;
    d.u = *(const uint4*)(p + h*512);
    #pragma unroll
    for (int j = 0; j < 8; ++j) s += bf2f(d.us[j]);
  }
  #pragma unroll
  for (int off = 1; off < 64; off <<= 1) s += __shfl_xor(s, off);
  if (l == 0) out[row] = 1.0f / s;
}

// ---------------------------------------------------------------------------
// Orchestration. ws (128 MiB): P16 | H16 | P16T | H16T(->ET).
// E lives in the b_tilde half of d_out (written last); small vectors live in
// the free tail of that half; rbInv overwrites the dead P16 slot.
// ---------------------------------------------------------------------------
extern "C" void kernel_launch(void* const* d_in, const int* in_sizes, int n_in,
                              void* d_out, int out_size, void* d_ws, size_t ws_size,
                              hipStream_t stream)
{
  const float* P  = (const float*)d_in[0];
  const float* Hp = (const float*)d_in[1];
  float* outF = (float*)d_out;
  float* aOut = outF;            // a_tilde: first NE floats
  float* bOut = outF + NE;       // b_tilde: next NE floats

  unsigned short* P16  = (unsigned short*)d_ws;
  unsigned short* H16  = P16  + NE;
  unsigned short* P16T = H16  + NE;
  unsigned short* H16T = P16T + NE;          // reused for ET after K3
  if (ws_size < 4 * NE * sizeof(unsigned short)) return;  // need 128 MiB scratch

  unsigned short* E = (unsigned short*)bOut;   // NE bf16 = first NE/2 floats of b-half
  float* smalls = bOut + NE/2;                 // free tail of b-half (33.5 MB)
  float* invP  = smalls;
  float* invH  = smalls + BATCH*SEQ;
  float* raInv = smalls + 2*BATCH*SEQ;
  float* rbInv = (float*)P16;                  // P16 dead once this is written

  dim3 blk(256);
  dim3 gg(BATCH, 8, 8);   // batch fastest -> same-batch tiles share an XCD's L2

  // 1) bf16 copies + transposes + inverse norms
  k_cvt<<<dim3(BATCH,16,2), blk, 0, stream>>>(P, Hp, P16, H16, P16T, H16T, invP, invH);
  // 2) E = exp(p_norm . h_norm^T)   [a][h], into b-half of d_out
  k_gemm<0><<<gg, blk, 0, stream>>>(P16, H16, (void*)E, invP, invH);
  // 3) raInv = 1/rowsum(E)
  k_rowinv<<<dim3(BATCH*SEQ/4), blk, 0, stream>>>(E, raInv);
  // 4) a_tilde = (E . H) * raInv    (B^T operand = H16T)
  k_gemm<1><<<gg, blk, 0, stream>>>(E, H16T, (void*)aOut, raInv, nullptr);
  // 5) ET = exp(h_norm . p_norm^T)  [h][a], into the now-dead H16T slot
  k_gemm<0><<<gg, blk, 0, stream>>>(H16, P16, (void*)H16T, invH, invP);
  // 6) rbInv = 1/rowsum(ET)
  k_rowinv<<<dim3(BATCH*SEQ/4), blk, 0, stream>>>(H16T, rbInv);
  // 7) b_tilde = (ET . P) * rbInv   (B^T operand = P16T)
  k_gemm<1><<<gg, blk, 0, stream>>>(H16T, P16T, (void*)bOut, rbInv, nullptr);
}